// Round 8
// baseline (405.877 us; speedup 1.0000x reference)
//
#include <hip/hip_runtime.h>
#include <hip/hip_bf16.h>

#define NB 128
#define NN 64
#define HH 128

typedef short bf16x8 __attribute__((ext_vector_type(8)));
typedef float f32x4 __attribute__((ext_vector_type(4)));

static inline int cdiv(int a, int b) { return (a + b - 1) / b; }

__device__ __forceinline__ float tanh_fast(float x) {
    float ax = fabsf(x);
    float ex = __expf(-2.0f * ax);
    float t  = (1.0f - ex) / (1.0f + ex);
    return copysignf(t, x);
}

// RNE float->bf16 (raw ushort) and back
__device__ __forceinline__ unsigned short f2bfs(float f) {
    unsigned u; __builtin_memcpy(&u, &f, 4);
    u = (u + 0x7FFFu + ((u >> 16) & 1u)) >> 16;
    return (unsigned short)u;
}
__device__ __forceinline__ float bfs2f(unsigned short s) {
    unsigned u = ((unsigned)s) << 16;
    float f; __builtin_memcpy(&f, &u, 4);
    return f;
}
__device__ __forceinline__ int pack2(unsigned short a, unsigned short b) {
    return (int)((unsigned)a | ((unsigned)b << 16));
}
__device__ __forceinline__ f32x4 mfma16(bf16x8 a, bf16x8 b, f32x4 c) {
    return __builtin_amdgcn_mfma_f32_16x16x32_bf16(a, b, c, 0, 0, 0);
}

// ---------- graph index prep ----------
__global__ void scatter_ids_kernel(const int* __restrict__ bI, const int* __restrict__ nI,
                                   const int* __restrict__ nhI, int* __restrict__ idmat, int E) {
    int e = blockIdx.x * blockDim.x + threadIdx.x;
    if (e >= E) return;
    idmat[((bI[e] << 6) + nI[e]) * NN + nhI[e]] = e;
}
// rev[e] = id of reverse edge (exists: A symmetric)
__global__ void build_rev_kernel(const int* __restrict__ bI, const int* __restrict__ nI,
                                 const int* __restrict__ nhI, const int* __restrict__ idmat,
                                 int* __restrict__ rev, int E) {
    int e = blockIdx.x * blockDim.x + threadIdx.x;
    if (e >= E) return;
    rev[e] = idmat[((bI[e] << 6) + nhI[e]) * NN + nI[e]];
}
// node_ptr[v] = lower_bound of seg(e)=b*64+n (edges sorted by (b,n,nhb))
__global__ void build_ptr_kernel(const int* __restrict__ bI, const int* __restrict__ nI,
                                 int E, int* __restrict__ ptr) {
    int v = blockIdx.x * blockDim.x + threadIdx.x;
    if (v > NB * NN) return;
    int lo = 0, hi = E;
    while (lo < hi) {
        int mid = (lo + hi) >> 1;
        int sg = (bI[mid] << 6) + nI[mid];
        if (sg < v) lo = mid + 1; else hi = mid;
    }
    ptr[v] = lo;
}
// transpose weights to bf16 WT[col][k]; K of W_emb zero-padded 144->160; zero g
__global__ void prep_w_kernel(const float* __restrict__ W_emb, const float* __restrict__ W_edge,
                              const float* __restrict__ W_msg,
                              unsigned short* __restrict__ WTe, unsigned short* __restrict__ WTd,
                              unsigned short* __restrict__ WTm, float* __restrict__ g) {
    int i = blockIdx.x * blockDim.x + threadIdx.x;
    if (i < 128 * 160) { int c = i / 160, k = i % 160;
        WTe[c * 160 + k] = f2bfs(k < 144 ? W_emb[k * 128 + c] : 0.f); return; }
    i -= 128 * 160;
    if (i < 128 * 128) { int c = i >> 7, k = i & 127;
        WTd[c * 128 + k] = f2bfs(W_edge[k * 128 + c]); return; }
    i -= 128 * 128;
    if (i < 128 * 128) { int c = i >> 7, k = i & 127;
        WTm[c * 128 + k] = f2bfs(W_msg[k * 128 + c]); return; }
    i -= 128 * 128;
    if (i < NB * HH) g[i] = 0.f;
}

// ---------- fused embed+edge GEMM: t = tanh(cat@W_emb+b_emb); ef2 = t@W_edge+b_prop;
//            mem1 = tanh(ef2)  (MP iter 1, since mem0 == 0) ----------
__global__ __launch_bounds__(256) void g01_kernel(
    const float* __restrict__ nodes, const float* __restrict__ edgesF,
    const unsigned short* __restrict__ WTe, const unsigned short* __restrict__ WTd,
    const float* __restrict__ b_emb, const float* __restrict__ b_prop,
    const int* __restrict__ bI, const int* __restrict__ nI, const int* __restrict__ nhI,
    float* __restrict__ ef2, unsigned short* __restrict__ mem1, int E)
{
    __shared__ __align__(16) char lds[51200];
    unsigned short* A = (unsigned short*)lds;          // [64][168] bf16 (K=160 padded)
    const int tid = threadIdx.x;
    const int e0  = blockIdx.x * 64;

    for (int s = tid; s < 1280; s += 256) {            // 64 rows * 20 k-groups
        int row = s / 20, kg = s % 20, k0 = kg * 8;
        int e = e0 + row;
        float f0=0,f1=0,f2=0,f3=0,f4=0,f5=0,f6=0,f7=0;
        if (e < E && k0 < 144) {
            int b = bI[e], n = nI[e], nh = nhI[e];
            const float* p;
            if (k0 < 64)        p = nodes  + ((((size_t)b << 6) + n)  << 6) + k0;
            else if (k0 < 128)  p = nodes  + ((((size_t)b << 6) + nh) << 6) + (k0 - 64);
            else                p = edgesF + ((((((size_t)b << 6) + n) << 6) + nh) << 4) + (k0 - 128);
            float4 x = *(const float4*)p, y = *(const float4*)(p + 4);
            f0=x.x; f1=x.y; f2=x.z; f3=x.w; f4=y.x; f5=y.y; f6=y.z; f7=y.w;
        }
        int4 w;
        w.x = pack2(f2bfs(f0), f2bfs(f1)); w.y = pack2(f2bfs(f2), f2bfs(f3));
        w.z = pack2(f2bfs(f4), f2bfs(f5)); w.w = pack2(f2bfs(f6), f2bfs(f7));
        *(int4*)&A[row * 168 + k0] = w;
    }
    __syncthreads();

    const int lane = tid & 63, wid = tid >> 6;
    const int wm = wid & 1, wn = wid >> 1;
    const int l15 = lane & 15, lk = lane >> 4;
    const int r0 = wm * 32, cb = wn * 64;

    f32x4 acc[2][4];
    #pragma unroll
    for (int mi = 0; mi < 2; ++mi)
        #pragma unroll
        for (int ni = 0; ni < 4; ++ni) acc[mi][ni] = (f32x4)0.f;

    #pragma unroll
    for (int ks = 0; ks < 5; ++ks) {                  // K=160
        bf16x8 a0 = *(const bf16x8*)&A[(r0 + l15)      * 168 + ks * 32 + lk * 8];
        bf16x8 a1 = *(const bf16x8*)&A[(r0 + 16 + l15) * 168 + ks * 32 + lk * 8];
        #pragma unroll
        for (int ni = 0; ni < 4; ++ni) {
            bf16x8 bb = *(const bf16x8*)&WTe[(size_t)(cb + ni * 16 + l15) * 160 + ks * 32 + lk * 8];
            acc[0][ni] = mfma16(a0, bb, acc[0][ni]);
            acc[1][ni] = mfma16(a1, bb, acc[1][ni]);
        }
    }
    __syncthreads();

    unsigned short* T = (unsigned short*)lds;          // t [64][136] bf16
    #pragma unroll
    for (int mi = 0; mi < 2; ++mi)
        #pragma unroll
        for (int ni = 0; ni < 4; ++ni) {
            int col = cb + ni * 16 + l15;
            float be = b_emb[col];
            #pragma unroll
            for (int j = 0; j < 4; ++j) {
                int row = r0 + mi * 16 + lk * 4 + j;
                T[row * 136 + col] = f2bfs(tanh_fast(acc[mi][ni][j] + be));
            }
        }
    __syncthreads();

    f32x4 acc2[2][4];
    #pragma unroll
    for (int mi = 0; mi < 2; ++mi)
        #pragma unroll
        for (int ni = 0; ni < 4; ++ni) acc2[mi][ni] = (f32x4)0.f;

    #pragma unroll
    for (int ks = 0; ks < 4; ++ks) {                  // K=128
        bf16x8 a0 = *(const bf16x8*)&T[(r0 + l15)      * 136 + ks * 32 + lk * 8];
        bf16x8 a1 = *(const bf16x8*)&T[(r0 + 16 + l15) * 136 + ks * 32 + lk * 8];
        #pragma unroll
        for (int ni = 0; ni < 4; ++ni) {
            bf16x8 bb = *(const bf16x8*)&WTd[(size_t)(cb + ni * 16 + l15) * 128 + ks * 32 + lk * 8];
            acc2[0][ni] = mfma16(a0, bb, acc2[0][ni]);
            acc2[1][ni] = mfma16(a1, bb, acc2[1][ni]);
        }
    }
    __syncthreads();

    float*          EF = (float*)lds;                           // [64][132]
    unsigned short* MB = (unsigned short*)(lds + 64 * 132 * 4); // [64][136]
    #pragma unroll
    for (int mi = 0; mi < 2; ++mi)
        #pragma unroll
        for (int ni = 0; ni < 4; ++ni) {
            int col = cb + ni * 16 + l15;
            float bp = b_prop[col];
            #pragma unroll
            for (int j = 0; j < 4; ++j) {
                int row = r0 + mi * 16 + lk * 4 + j;
                float z = acc2[mi][ni][j] + bp;
                EF[row * 132 + col] = z;
                MB[row * 136 + col] = f2bfs(tanh_fast(z));
            }
        }
    __syncthreads();
    for (int s = tid; s < 2048; s += 256) {
        int row = s >> 5, c0 = (s & 31) * 4, e = e0 + row;
        if (e < E) *(float4*)&ef2[(size_t)e * HH + c0] = *(const float4*)&EF[row * 132 + c0];
    }
    for (int s = tid; s < 1024; s += 256) {
        int row = s >> 4, c0 = (s & 15) * 8, e = e0 + row;
        if (e < E) *(int4*)&mem1[(size_t)e * HH + c0] = *(const int4*)&MB[row * 136 + c0];
    }
}

// ---------- fused MP iteration, node-centric, 4 nodes/block (1 independent wave each).
// For f in out(u) (contiguous rows s..e1): edges e with nh(e)=u are exactly rev(f), and
// msg[rev(f)] = S[u] - mem[f],  S[u] = sum of the same contiguous rows.
// Operand-swapped MFMA: D = mfma(A=W^T frag, B=msg frag) -> lane l15 owns edge col,
// rows lk*4+j are features -> per-lane float4 ef2 loads + 8B memOut stores, no LDS bounce.
template <int LAST>
__global__ __launch_bounds__(256) void mp_kernel(
    const unsigned short* __restrict__ memIn, const float* __restrict__ ef2,
    const unsigned short* __restrict__ WTm, const int* __restrict__ rev,
    const int* __restrict__ ptr, unsigned short* __restrict__ memOut,
    float* __restrict__ g)
{
    const int wv   = threadIdx.x >> 6;
    const int u    = (blockIdx.x << 2) + wv;
    const int lane = threadIdx.x & 63;
    const int l15  = lane & 15, lk = lane >> 4;

    __shared__ float Sall[4][132];        // per-wave S slice; no cross-wave sharing
    float* S = Sall[wv];

    const int s   = ptr[u], e1 = ptr[u + 1];
    const int deg = e1 - s;
    if (deg == 0) return;                 // per-wave exit; kernel has NO block barriers

    // ---- S[k] = column sums of mem rows s..e1 (2 cols/lane) ----
    {
        float s0 = 0.f, s1 = 0.f;
        for (int r = 0; r < deg; ++r) {
            s0 += bfs2f(memIn[(size_t)(s + r) * HH + lane]);
            s1 += bfs2f(memIn[(size_t)(s + r) * HH + lane + 64]);
        }
        S[lane] = s0; S[lane + 64] = s1;
    }
    __threadfence_block();                // order this wave's LDS write -> read

    float gacc[8][4];
    if (LAST) {
        #pragma unroll
        for (int ni = 0; ni < 8; ++ni)
            #pragma unroll
            for (int j = 0; j < 4; ++j) gacc[ni][j] = 0.f;
    }

    for (int c0 = 0; c0 < deg; c0 += 16) {
        const int  nrows = min(16, deg - c0);
        const bool valid = (l15 < nrows);
        const int  erow  = s + c0 + l15;
        const int  rv    = valid ? rev[erow] : 0;

        f32x4 acc[8];
        #pragma unroll
        for (int ni = 0; ni < 8; ++ni) acc[ni] = (f32x4)0.f;

        #pragma unroll
        for (int ks = 0; ks < 4; ++ks) {
            // B-fragment: msg[k][edge=l15] = bf16(S[k] - mem[erow][k]), k = ks*32+lk*8+q
            bf16x8 bfrag;
            {
                float4 sa = *(const float4*)&S[ks * 32 + lk * 8];
                float4 sb = *(const float4*)&S[ks * 32 + lk * 8 + 4];
                int4 mr = make_int4(0, 0, 0, 0);
                if (valid) mr = *(const int4*)&memIn[(size_t)erow * HH + ks * 32 + lk * 8];
                unsigned short h[8];
                #pragma unroll
                for (int q = 0; q < 4; ++q) {
                    int raw = (&mr.x)[q];
                    float lo = bfs2f((unsigned short)(raw & 0xFFFF));
                    float hi = bfs2f((unsigned short)((unsigned)raw >> 16));
                    float sv0 = (q < 2) ? ((q == 0) ? sa.x : sa.z) : ((q == 2) ? sb.x : sb.z);
                    float sv1 = (q < 2) ? ((q == 0) ? sa.y : sa.w) : ((q == 2) ? sb.y : sb.w);
                    h[2 * q]     = f2bfs(sv0 - lo);
                    h[2 * q + 1] = f2bfs(sv1 - hi);
                }
                #pragma unroll
                for (int q = 0; q < 8; ++q) bfrag[q] = (short)h[q];
                if (!valid) {
                    #pragma unroll
                    for (int q = 0; q < 8; ++q) bfrag[q] = 0;   // keep pad cols clean
                }
            }
            #pragma unroll
            for (int ni = 0; ni < 8; ++ni) {
                bf16x8 afrag = *(const bf16x8*)&WTm[(size_t)(ni * 16 + l15) * HH + ks * 32 + lk * 8];
                acc[ni] = mfma16(afrag, bfrag, acc[ni]);
            }
        }

        // D: col=l15=edge, row=lk*4+j -> feature f = ni*16 + lk*4 + j
        if (valid) {
            if (!LAST) {
                #pragma unroll
                for (int ni = 0; ni < 8; ++ni) {
                    int f0 = ni * 16 + lk * 4;
                    float4 ef = *(const float4*)&ef2[(size_t)rv * HH + f0];
                    unsigned short h0 = f2bfs(tanh_fast(acc[ni][0] + ef.x));
                    unsigned short h1 = f2bfs(tanh_fast(acc[ni][1] + ef.y));
                    unsigned short h2 = f2bfs(tanh_fast(acc[ni][2] + ef.z));
                    unsigned short h3 = f2bfs(tanh_fast(acc[ni][3] + ef.w));
                    uint2 o;
                    o.x = (unsigned)pack2(h0, h1);
                    o.y = (unsigned)pack2(h2, h3);
                    *(uint2*)&memOut[(size_t)rv * HH + f0] = o;
                }
            } else {
                #pragma unroll
                for (int ni = 0; ni < 8; ++ni) {
                    int f0 = ni * 16 + lk * 4;
                    float4 ef = *(const float4*)&ef2[(size_t)rv * HH + f0];
                    gacc[ni][0] += tanh_fast(acc[ni][0] + ef.x);
                    gacc[ni][1] += tanh_fast(acc[ni][1] + ef.y);
                    gacc[ni][2] += tanh_fast(acc[ni][2] + ef.z);
                    gacc[ni][3] += tanh_fast(acc[ni][3] + ef.w);
                }
            }
        }
    }

    if (LAST) {
        // reduce over the 16 edge-lanes (l15) within each lk group
        #pragma unroll
        for (int ni = 0; ni < 8; ++ni)
            #pragma unroll
            for (int j = 0; j < 4; ++j) {
                float v = gacc[ni][j];
                v += __shfl_xor(v, 1); v += __shfl_xor(v, 2);
                v += __shfl_xor(v, 4); v += __shfl_xor(v, 8);
                gacc[ni][j] = v;
            }
        if (l15 == 0) {
            const int b = u >> 6;
            #pragma unroll
            for (int ni = 0; ni < 8; ++ni)
                #pragma unroll
                for (int j = 0; j < 4; ++j)
                    atomicAdd(&g[(size_t)b * HH + ni * 16 + lk * 4 + j], gacc[ni][j]);
        }
    }
}

// out[b] = g[b] @ W_out + b_out
__global__ void out2_kernel(const float* __restrict__ g, const float* __restrict__ W_out,
                            const float* __restrict__ b_out, float* __restrict__ out) {
    int b = blockIdx.x, tid = threadIdx.x;
    if (tid < 32) {
        float a = b_out[tid];
        for (int h = 0; h < HH; ++h) a += g[(size_t)b * HH + h] * W_out[h * 32 + tid];
        out[b * 32 + tid] = a;
    }
}

extern "C" void kernel_launch(void* const* d_in, const int* in_sizes, int n_in,
                              void* d_out, int out_size, void* d_ws, size_t ws_size,
                              hipStream_t stream) {
    const float* nodes  = (const float*)d_in[0];
    const float* edgesF = (const float*)d_in[1];
    const float* W_emb  = (const float*)d_in[2];
    const float* b_emb  = (const float*)d_in[3];
    const float* W_msg  = (const float*)d_in[4];
    const float* W_edge = (const float*)d_in[5];
    const float* b_prop = (const float*)d_in[6];
    const float* W_out  = (const float*)d_in[7];
    const float* b_out  = (const float*)d_in[8];
    const int*   bI     = (const int*)d_in[9];
    const int*   nI     = (const int*)d_in[10];
    const int*   nhI    = (const int*)d_in[11];
    const int    E      = in_sizes[9];
    float*       out    = (float*)d_out;

    char* ws = (char*)d_ws;
    size_t al = 255;
    size_t szEf  = (((size_t)E * HH * 4) + al) & ~al;
    size_t szMem = (((size_t)E * HH * 2) + al) & ~al;
    size_t szI   = (((size_t)E * 4) + al) & ~al;
    float*          ef2   = (float*)ws;                      ws += szEf;
    unsigned short* memA  = (unsigned short*)ws;             ws += szMem;
    unsigned short* memB  = (unsigned short*)ws;             ws += szMem;
    float*          g     = (float*)ws;                      ws += (size_t)NB * HH * 4;
    int*            idmat = (int*)ws;                        ws += (size_t)NB * NN * NN * 4;
    int*            rev   = (int*)ws;                        ws += szI;
    int*            ptr   = (int*)ws;                        ws += (((size_t)(NB * NN + 1) * 4) + al) & ~al;
    unsigned short* WTe   = (unsigned short*)ws;             ws += 128 * 160 * 2;
    unsigned short* WTd   = (unsigned short*)ws;             ws += 128 * 128 * 2;
    unsigned short* WTm   = (unsigned short*)ws;             ws += 128 * 128 * 2;

    scatter_ids_kernel<<<cdiv(E, 256), 256, 0, stream>>>(bI, nI, nhI, idmat, E);
    build_rev_kernel  <<<cdiv(E, 256), 256, 0, stream>>>(bI, nI, nhI, idmat, rev, E);
    build_ptr_kernel  <<<cdiv(NB * NN + 1, 256), 256, 0, stream>>>(bI, nI, E, ptr);
    prep_w_kernel     <<<cdiv(128 * 160 + 2 * 128 * 128 + NB * HH, 256), 256, 0, stream>>>(
                        W_emb, W_edge, W_msg, WTe, WTd, WTm, g);

    const int gb = cdiv(E, 64);
    g01_kernel<<<gb, 256, 0, stream>>>(nodes, edgesF, WTe, WTd, b_emb, b_prop,
                                       bI, nI, nhI, ef2, memA, E);
    // MP iters 2..4 (fused node-sum + edge GEMM, node-centric, 4 nodes/block)
    mp_kernel<0><<<NB * NN / 4, 256, 0, stream>>>(memA, ef2, WTm, rev, ptr, memB, nullptr);
    mp_kernel<0><<<NB * NN / 4, 256, 0, stream>>>(memB, ef2, WTm, rev, ptr, memA, nullptr);
    mp_kernel<1><<<NB * NN / 4, 256, 0, stream>>>(memA, ef2, WTm, rev, ptr, nullptr, g);

    out2_kernel<<<NB, 64, 0, stream>>>(g, W_out, b_out, out);
}